// Round 8
// baseline (123.304 us; speedup 1.0000x reference)
//
#include <hip/hip_runtime.h>
#include <hip/hip_bf16.h>

#define B_ 4
#define T_ 128
#define U_ 64
#define D_ 512
#define H_ 640
#define V_ 1024

typedef float f32x4 __attribute__((ext_vector_type(4)));
typedef __bf16 bf16x8 __attribute__((ext_vector_type(8)));

union U4BF8 { uint4 u; bf16x8 v; };

__device__ __forceinline__ unsigned short f2bf(float x) {
  union { float f; unsigned int u; } a; a.f = x;
  unsigned int r = a.u + 0x7FFFu + ((a.u >> 16) & 1u);
  return (unsigned short)(r >> 16);
}

// ---------------------------------------------------------------------------
// P0: pack W2 -> bf16 fragment cells with COLUMN PERMUTE: packed position
// p = wid*64 + nf*16 + l16 holds original col wid*64 + l16*4 + nf, so a
// lane's 4 nf-accumulators are 4 consecutive output cols (dwordx4 stores).
// ---------------------------------------------------------------------------
__global__ void k_pack_w2(const float* __restrict__ W2, uint4* __restrict__ w2p,
                          const int* __restrict__ slen, const int* __restrict__ tlen,
                          float* __restrict__ out_tail) {
  int kq = blockIdx.x;           // 0..79
  int tid = threadIdx.x;         // 256
  for (int i = 0; i < 4; ++i) {
    int n = tid + i * 256;
    int src_n = (n & ~63) | ((n & 15) * 4) | ((n >> 4) & 3);
    float f[8];
    #pragma unroll
    for (int j = 0; j < 8; ++j) f[j] = W2[(size_t)(kq * 8 + j) * V_ + src_n];
    unsigned int w[4];
    #pragma unroll
    for (int j = 0; j < 4; ++j)
      w[j] = (unsigned)f2bf(f[2 * j]) | ((unsigned)f2bf(f[2 * j + 1]) << 16);
    uint4 p; p.x = w[0]; p.y = w[1]; p.z = w[2]; p.w = w[3];
    w2p[(size_t)kq * V_ + n] = p;
  }
  if (blockIdx.x == 0 && tid < 8)
    out_tail[tid] = (tid < 4) ? (float)slen[tid] : (float)tlen[tid - 4];
}

// ---------------------------------------------------------------------------
// P1: ps = SRC @ W1[:D]  (512x640);  pt = TGT @ W1[D:] + b1  (256x640), f32.
// ---------------------------------------------------------------------------
__global__ __launch_bounds__(640) void k_proj(
    const float* __restrict__ src, const float* __restrict__ tgt,
    const float* __restrict__ W1, const float* __restrict__ b1,
    float* __restrict__ ps, float* __restrict__ pt) {
  __shared__ __align__(16) float lin[D_ * 4];
  int bid = blockIdx.x, tid = threadIdx.x;
  bool is_t = bid >= 128;
  const float* in; const float* w; float* outp;
  if (!is_t) {
    int r0 = bid * 4;
    in = src + (size_t)r0 * D_; w = W1; outp = ps + (size_t)r0 * H_;
  } else {
    int r0 = (bid - 128) * 4;
    in = tgt + (size_t)r0 * D_; w = W1 + (size_t)D_ * H_; outp = pt + (size_t)r0 * H_;
  }
  for (int idx = tid; idx < 4 * D_; idx += 640) {
    int r = idx >> 9, k = idx & (D_ - 1);
    lin[k * 4 + r] = in[idx];
  }
  __syncthreads();
  float a0 = 0.f, a1 = 0.f, a2 = 0.f, a3 = 0.f;
  int j = tid;
  for (int k = 0; k < D_; ++k) {
    float wv = w[(size_t)k * H_ + j];
    f32x4 x = *(const f32x4*)&lin[k * 4];
    a0 += x[0] * wv; a1 += x[1] * wv; a2 += x[2] * wv; a3 += x[3] * wv;
  }
  float bb = is_t ? b1[j] : 0.f;
  outp[0 * H_ + j] = a0 + bb;
  outp[1 * H_ + j] = a1 + bb;
  outp[2 * H_ + j] = a2 + bb;
  outp[3 * H_ + j] = a3 + bb;
}

// ---------------------------------------------------------------------------
// Main: 512 blocks x 1024 threads, one (b,t) each. CHUNKED-FUSED pipeline:
// K=640 split into 5 chunks of 16 kq (K=128). Per chunk each thread gens
// exactly ONE A-cell (m=tid>>4, kq=tid&15 -- no division) into the LDS
// back-buffer (16KB) while the MFMA loop consumes the front-buffer; one
// barrier per chunk. A-gen VALU/trans + gen loads now overlap MFMA + B-load
// L2 latency across the whole kernel instead of a serial 80KB P1 phase.
// LDS 90->41KB. NO loop-carried B prefetch (r4 spill lesson: gen temps die
// before the MFMA section; acc 64 AGPR + ~60 VGPR fits the 128 cap).
// Swizzle: cell(m,kq) at [m*16 + (kq^(m&7))]: writes contiguous-permuted
// (floor), reads uniform 8 lanes/bank-group (floor).
// ---------------------------------------------------------------------------
__global__ __launch_bounds__(1024, 4) void k_joint(
    const float* __restrict__ ps, const float* __restrict__ pt,
    const uint4* __restrict__ w2p, const float* __restrict__ b2,
    float* __restrict__ out) {
  __shared__ uint4 ldsA[2][64 * 16];       // 2 x 16KB double buffer
  __shared__ float red[16][64][2];         // 8KB
  __shared__ float lzs[64];
  int bid = blockIdx.x;                    // 0..511
  int xcd = bid & 7;
  int b = xcd >> 1;                        // one batch per XCD pair
  int t = (bid >> 3) + (xcd & 1) * 64;     // 0..127
  int tid = threadIdx.x;
  int lane = tid & 63, wid = tid >> 6;     // wid 0..15
  int l16 = lane & 15, lg = lane >> 4;
  int xs = l16 & 7;
  int gm = tid >> 4;                       // gen row 0..63
  int gk = tid & 15;                       // gen kq-local 0..15
  int gcell = gm * 16 + (gk ^ (gm & 7));   // swizzled gen cell
  const float* psrow = ps + (size_t)(b * T_ + t) * H_;
  const float* ptrow = pt + (size_t)(b * U_ + gm) * H_;

  f32x4 acc[4][4];
  #pragma unroll
  for (int mf = 0; mf < 4; ++mf)
    #pragma unroll
    for (int nf = 0; nf < 4; ++nf) {
      f32x4 z = {0.f, 0.f, 0.f, 0.f};
      acc[mf][nf] = z;
    }

#define GEN_CHUNK(CK, BUF)                                                    \
  {                                                                           \
    int kq = (CK) * 16 + gk;                                                  \
    const float4* pp = (const float4*)(psrow + kq * 8);                       \
    const float4* qq = (const float4*)(ptrow + kq * 8);                       \
    float4 p0 = pp[0], p1 = pp[1];                                            \
    float4 q0 = qq[0], q1 = qq[1];                                            \
    float x[8] = {p0.x + q0.x, p0.y + q0.y, p0.z + q0.z, p0.w + q0.w,         \
                  p1.x + q1.x, p1.y + q1.y, p1.z + q1.z, p1.w + q1.w};        \
    unsigned int wv[4];                                                       \
    _Pragma("unroll")                                                         \
    for (int j = 0; j < 4; ++j) {                                             \
      float e0 = __expf(2.f * x[2 * j]);                                      \
      float h0 = 1.f - 2.f * __builtin_amdgcn_rcpf(e0 + 1.f);                 \
      float e1 = __expf(2.f * x[2 * j + 1]);                                  \
      float h1 = 1.f - 2.f * __builtin_amdgcn_rcpf(e1 + 1.f);                 \
      wv[j] = (unsigned)f2bf(h0) | ((unsigned)f2bf(h1) << 16);                \
    }                                                                         \
    uint4 pk; pk.x = wv[0]; pk.y = wv[1]; pk.z = wv[2]; pk.w = wv[3];         \
    ldsA[BUF][gcell] = pk;                                                    \
  }

  GEN_CHUNK(0, 0);

  for (int ck = 0; ck < 5; ++ck) {
    __syncthreads();                       // gen(ck) visible; buf free
    if (ck < 4) GEN_CHUNK(ck + 1, (ck + 1) & 1);
    const uint4* bufA = ldsA[ck & 1];
    #pragma unroll
    for (int kq0 = 0; kq0 < 16; kq0 += 4) {
      int kql = kq0 + lg;                  // 0..15
      U4BF8 a[4];
      #pragma unroll
      for (int mf = 0; mf < 4; ++mf)
        a[mf].u = bufA[(mf * 16 + l16) * 16 + (kql ^ xs)];
      const uint4* bp = w2p + (size_t)(ck * 16 + kql) * 1024 + wid * 64 + l16;
      #pragma unroll
      for (int nf = 0; nf < 4; ++nf) {
        U4BF8 bb; bb.u = bp[nf * 16];
        #pragma unroll
        for (int mf = 0; mf < 4; ++mf)
          acc[mf][nf] = __builtin_amdgcn_mfma_f32_16x16x32_bf16(
              a[mf].v, bb.v, acc[mf][nf], 0, 0, 0);
      }
    }
  }
#undef GEN_CHUNK

  // ---- epilogue: fold b2 (permuted cols), log_softmax, nt float4 store ----
  {
    f32x4 b2v = *(const f32x4*)&b2[wid * 64 + l16 * 4];
    #pragma unroll
    for (int mf = 0; mf < 4; ++mf)
      #pragma unroll
      for (int nf = 0; nf < 4; ++nf)
        #pragma unroll
        for (int r = 0; r < 4; ++r)
          acc[mf][nf][r] += b2v[nf];
  }

  #pragma unroll
  for (int mf = 0; mf < 4; ++mf)
    #pragma unroll
    for (int r = 0; r < 4; ++r) {
      float pm = -3.4e38f;
      #pragma unroll
      for (int nf = 0; nf < 4; ++nf) pm = fmaxf(pm, acc[mf][nf][r]);
      pm = fmaxf(pm, __shfl_xor(pm, 1));
      pm = fmaxf(pm, __shfl_xor(pm, 2));
      pm = fmaxf(pm, __shfl_xor(pm, 4));
      pm = fmaxf(pm, __shfl_xor(pm, 8));
      float s = 0.f;
      #pragma unroll
      for (int nf = 0; nf < 4; ++nf) s += __expf(acc[mf][nf][r] - pm);
      s += __shfl_xor(s, 1);
      s += __shfl_xor(s, 2);
      s += __shfl_xor(s, 4);
      s += __shfl_xor(s, 8);
      if (l16 == 0) {
        int row = mf * 16 + lg * 4 + r;
        red[wid][row][0] = pm;
        red[wid][row][1] = s;
      }
    }
  __syncthreads();

  if (tid < 64) {
    float M = -3.4e38f;
    #pragma unroll
    for (int w16 = 0; w16 < 16; ++w16) M = fmaxf(M, red[w16][tid][0]);
    float S = 0.f;
    #pragma unroll
    for (int w16 = 0; w16 < 16; ++w16)
      S += red[w16][tid][1] * __expf(red[w16][tid][0] - M);
    lzs[tid] = M + __logf(S);
  }
  __syncthreads();

  float* outb = out + (size_t)(b * T_ + t) * U_ * V_;
  #pragma unroll
  for (int mf = 0; mf < 4; ++mf)
    #pragma unroll
    for (int r = 0; r < 4; ++r) {
      int row = mf * 16 + lg * 4 + r;
      float lz = lzs[row];
      f32x4 o;
      o[0] = acc[mf][0][r] - lz;
      o[1] = acc[mf][1][r] - lz;
      o[2] = acc[mf][2][r] - lz;
      o[3] = acc[mf][3][r] - lz;
      __builtin_nontemporal_store(
          o, (f32x4*)&outb[(size_t)row * V_ + wid * 64 + l16 * 4]);
    }
}

extern "C" void kernel_launch(void* const* d_in, const int* in_sizes, int n_in,
                              void* d_out, int out_size, void* d_ws, size_t ws_size,
                              hipStream_t stream) {
  const float* src = (const float*)d_in[0];
  const int*   slen = (const int*)d_in[1];
  const float* tgt = (const float*)d_in[2];
  const int*   tlen = (const int*)d_in[3];
  const float* W1 = (const float*)d_in[4];
  const float* b1 = (const float*)d_in[5];
  const float* W2 = (const float*)d_in[6];
  const float* b2 = (const float*)d_in[7];
  float* out = (float*)d_out;

  float* ps  = (float*)d_ws;                 // 512*640 f32
  float* pt  = ps + 512 * 640;               // 256*640 f32
  uint4* w2p = (uint4*)(pt + 256 * 640);     // 80*1024 uint4 (bf16 packed W2)

  k_pack_w2<<<80, 256, 0, stream>>>(W2, w2p, slen, tlen,
                                    out + (size_t)B_ * T_ * U_ * V_);
  k_proj<<<192, 640, 0, stream>>>(src, tgt, W1, b1, ps, pt);
  k_joint<<<512, 1024, 0, stream>>>(ps, pt, w2p, b2, out);
}

// Round 9
// 113.408 us; speedup vs baseline: 1.0873x; 1.0873x over previous
//
#include <hip/hip_runtime.h>
#include <hip/hip_bf16.h>

#define B_ 4
#define T_ 128
#define U_ 64
#define D_ 512
#define H_ 640
#define V_ 1024

typedef float f32x4 __attribute__((ext_vector_type(4)));
typedef __bf16 bf16x8 __attribute__((ext_vector_type(8)));

union U4BF8 { uint4 u; bf16x8 v; };

__device__ __forceinline__ unsigned short f2bf(float x) {
  union { float f; unsigned int u; } a; a.f = x;
  unsigned int r = a.u + 0x7FFFu + ((a.u >> 16) & 1u);
  return (unsigned short)(r >> 16);
}

// ---------------------------------------------------------------------------
// P0: pack W2 -> bf16 fragment cells with COLUMN PERMUTE: packed position
// p = wid*64 + nf*16 + l16 holds original col wid*64 + l16*4 + nf, so a
// lane's 4 nf-accumulators are 4 consecutive output cols (dwordx4 stores).
// ---------------------------------------------------------------------------
__global__ void k_pack_w2(const float* __restrict__ W2, uint4* __restrict__ w2p,
                          const int* __restrict__ slen, const int* __restrict__ tlen,
                          float* __restrict__ out_tail) {
  int kq = blockIdx.x;           // 0..79
  int tid = threadIdx.x;         // 256
  for (int i = 0; i < 4; ++i) {
    int n = tid + i * 256;
    int src_n = (n & ~63) | ((n & 15) * 4) | ((n >> 4) & 3);
    float f[8];
    #pragma unroll
    for (int j = 0; j < 8; ++j) f[j] = W2[(size_t)(kq * 8 + j) * V_ + src_n];
    unsigned int w[4];
    #pragma unroll
    for (int j = 0; j < 4; ++j)
      w[j] = (unsigned)f2bf(f[2 * j]) | ((unsigned)f2bf(f[2 * j + 1]) << 16);
    uint4 p; p.x = w[0]; p.y = w[1]; p.z = w[2]; p.w = w[3];
    w2p[(size_t)kq * V_ + n] = p;
  }
  if (blockIdx.x == 0 && tid < 8)
    out_tail[tid] = (tid < 4) ? (float)slen[tid] : (float)tlen[tid - 4];
}

// ---------------------------------------------------------------------------
// P1: ps = SRC @ W1[:D]  (512x640);  pt = TGT @ W1[D:] + b1  (256x640), f32.
// ---------------------------------------------------------------------------
__global__ __launch_bounds__(640) void k_proj(
    const float* __restrict__ src, const float* __restrict__ tgt,
    const float* __restrict__ W1, const float* __restrict__ b1,
    float* __restrict__ ps, float* __restrict__ pt) {
  __shared__ __align__(16) float lin[D_ * 4];
  int bid = blockIdx.x, tid = threadIdx.x;
  bool is_t = bid >= 128;
  const float* in; const float* w; float* outp;
  if (!is_t) {
    int r0 = bid * 4;
    in = src + (size_t)r0 * D_; w = W1; outp = ps + (size_t)r0 * H_;
  } else {
    int r0 = (bid - 128) * 4;
    in = tgt + (size_t)r0 * D_; w = W1 + (size_t)D_ * H_; outp = pt + (size_t)r0 * H_;
  }
  for (int idx = tid; idx < 4 * D_; idx += 640) {
    int r = idx >> 9, k = idx & (D_ - 1);
    lin[k * 4 + r] = in[idx];
  }
  __syncthreads();
  float a0 = 0.f, a1 = 0.f, a2 = 0.f, a3 = 0.f;
  int j = tid;
  for (int k = 0; k < D_; ++k) {
    float wv = w[(size_t)k * H_ + j];
    f32x4 x = *(const f32x4*)&lin[k * 4];
    a0 += x[0] * wv; a1 += x[1] * wv; a2 += x[2] * wv; a3 += x[3] * wv;
  }
  float bb = is_t ? b1[j] : 0.f;
  outp[0 * H_ + j] = a0 + bb;
  outp[1 * H_ + j] = a1 + bb;
  outp[2 * H_ + j] = a2 + bb;
  outp[3 * H_ + j] = a3 + bb;
}

// ---------------------------------------------------------------------------
// Main: 512 blocks x 1024 threads (R7 bulk-phase structure), one (b,t) each.
// CHANGE vs R7: A-LDS layout is PADDED-AFFINE, not XOR-swizzled:
//   cell(m,kq) at ldsA[m*81 + kq]   (81-cell row = 1296B = 4 banks offset)
//   - gen (m=tid>>4, kq=i*16+(tid&15)): no div, coalesced ps/pt loads,
//     lane-contiguous writes (2-way quarter-conflict, free-ish).
//   - MFMA A-read: addr = (l16*81 + lg + kq0) cells + mf*20736B immediate
//     -> ONE v_add per iter; 2-way quarter-conflict (same as XOR layout).
//   - B pointer: += 64KB const per iter, nf at 1/2/3KB immediate offsets.
// Rationale: R7 spent 24us of VALU-issue (~44 instr/wave/iter) recomputing
// non-affine XOR addresses; every VALU slot blocks an MFMA issue slot.
// bb[4] die in-iter (no loop-carried state -> no r4-style spill).
// ---------------------------------------------------------------------------
__global__ __launch_bounds__(1024, 4) void k_joint(
    const float* __restrict__ ps, const float* __restrict__ pt,
    const uint4* __restrict__ w2p, const float* __restrict__ b2,
    float* __restrict__ out) {
  __shared__ uint4 ldsA[64 * 81];          // 81 KiB, [m][kq] padded rows
  __shared__ float red[16][64][2];         // 8 KiB
  __shared__ float lzs[64];
  int bid = blockIdx.x;                    // 0..511
  int xcd = bid & 7;
  int b = xcd >> 1;                        // one batch per XCD pair
  int t = (bid >> 3) + (xcd & 1) * 64;     // 0..127
  int tid = threadIdx.x;
  int lane = tid & 63, wid = tid >> 6;     // wid 0..15
  int l16 = lane & 15, lg = lane >> 4;
  const float* psrow = ps + (size_t)(b * T_ + t) * H_;

  // ---- phase 1: A generation: thread owns row gm, cols i*16+gk16 ----
  {
    int gm = tid >> 4;                     // 0..63
    int gk = tid & 15;
    const float* ptrow = pt + (size_t)(b * U_ + gm) * H_;
    uint4* wrow = &ldsA[gm * 81];
    #pragma unroll
    for (int i = 0; i < 5; ++i) {
      int kq = i * 16 + gk;
      const float4* pp = (const float4*)(psrow + kq * 8);
      const float4* qq = (const float4*)(ptrow + kq * 8);
      float4 p0 = pp[0], p1 = pp[1];
      float4 q0 = qq[0], q1 = qq[1];
      float x[8] = {p0.x + q0.x, p0.y + q0.y, p0.z + q0.z, p0.w + q0.w,
                    p1.x + q1.x, p1.y + q1.y, p1.z + q1.z, p1.w + q1.w};
      unsigned int wv[4];
      #pragma unroll
      for (int j = 0; j < 4; ++j) {
        float e0 = __expf(2.f * x[2 * j]);
        float h0 = 1.f - 2.f * __builtin_amdgcn_rcpf(e0 + 1.f);
        float e1 = __expf(2.f * x[2 * j + 1]);
        float h1 = 1.f - 2.f * __builtin_amdgcn_rcpf(e1 + 1.f);
        wv[j] = (unsigned)f2bf(h0) | ((unsigned)f2bf(h1) << 16);
      }
      uint4 pk; pk.x = wv[0]; pk.y = wv[1]; pk.z = wv[2]; pk.w = wv[3];
      wrow[kq] = pk;
    }
  }
  __syncthreads();

  f32x4 acc[4][4];
  #pragma unroll
  for (int mf = 0; mf < 4; ++mf)
    #pragma unroll
    for (int nf = 0; nf < 4; ++nf) {
      f32x4 z = {0.f, 0.f, 0.f, 0.f};
      acc[mf][nf] = z;
    }

  // ---- phase 2: K loop (20 iters of K=32), fully affine addressing ----
  {
    const uint4* arow = ldsA + l16 * 81 + lg;        // + kq0 per iter
    const uint4* bp   = w2p + wid * 64 + l16 + (size_t)lg * 1024;
    for (int kq0 = 0; kq0 < 80; kq0 += 4) {
      U4BF8 a[4];
      #pragma unroll
      for (int mf = 0; mf < 4; ++mf)
        a[mf].u = arow[mf * (16 * 81) + kq0];        // mf: 20736B immediates
      U4BF8 bb[4];
      const uint4* bpi = bp + (size_t)kq0 * 1024;
      #pragma unroll
      for (int nf = 0; nf < 4; ++nf) bb[nf].u = bpi[nf * 16];
      #pragma unroll
      for (int nf = 0; nf < 4; ++nf)
        #pragma unroll
        for (int mf = 0; mf < 4; ++mf)
          acc[mf][nf] = __builtin_amdgcn_mfma_f32_16x16x32_bf16(
              a[mf].v, bb[nf].v, acc[mf][nf], 0, 0, 0);
    }
  }

  // ---- phase 3: fold b2 (permuted cols), log_softmax, nt float4 store ----
  {
    f32x4 b2v = *(const f32x4*)&b2[wid * 64 + l16 * 4];
    #pragma unroll
    for (int mf = 0; mf < 4; ++mf)
      #pragma unroll
      for (int nf = 0; nf < 4; ++nf)
        #pragma unroll
        for (int r = 0; r < 4; ++r)
          acc[mf][nf][r] += b2v[nf];
  }

  #pragma unroll
  for (int mf = 0; mf < 4; ++mf)
    #pragma unroll
    for (int r = 0; r < 4; ++r) {
      float pm = -3.4e38f;
      #pragma unroll
      for (int nf = 0; nf < 4; ++nf) pm = fmaxf(pm, acc[mf][nf][r]);
      pm = fmaxf(pm, __shfl_xor(pm, 1));
      pm = fmaxf(pm, __shfl_xor(pm, 2));
      pm = fmaxf(pm, __shfl_xor(pm, 4));
      pm = fmaxf(pm, __shfl_xor(pm, 8));
      float s = 0.f;
      #pragma unroll
      for (int nf = 0; nf < 4; ++nf) s += __expf(acc[mf][nf][r] - pm);
      s += __shfl_xor(s, 1);
      s += __shfl_xor(s, 2);
      s += __shfl_xor(s, 4);
      s += __shfl_xor(s, 8);
      if (l16 == 0) {
        int row = mf * 16 + lg * 4 + r;
        red[wid][row][0] = pm;
        red[wid][row][1] = s;
      }
    }
  __syncthreads();

  if (tid < 64) {
    float M = -3.4e38f;
    #pragma unroll
    for (int w16 = 0; w16 < 16; ++w16) M = fmaxf(M, red[w16][tid][0]);
    float S = 0.f;
    #pragma unroll
    for (int w16 = 0; w16 < 16; ++w16)
      S += red[w16][tid][1] * __expf(red[w16][tid][0] - M);
    lzs[tid] = M + __logf(S);
  }
  __syncthreads();

  float* outb = out + (size_t)(b * T_ + t) * U_ * V_;
  #pragma unroll
  for (int mf = 0; mf < 4; ++mf)
    #pragma unroll
    for (int r = 0; r < 4; ++r) {
      int row = mf * 16 + lg * 4 + r;
      float lz = lzs[row];
      f32x4 o;
      o[0] = acc[mf][0][r] - lz;
      o[1] = acc[mf][1][r] - lz;
      o[2] = acc[mf][2][r] - lz;
      o[3] = acc[mf][3][r] - lz;
      __builtin_nontemporal_store(
          o, (f32x4*)&outb[(size_t)row * V_ + wid * 64 + l16 * 4]);
    }
}

extern "C" void kernel_launch(void* const* d_in, const int* in_sizes, int n_in,
                              void* d_out, int out_size, void* d_ws, size_t ws_size,
                              hipStream_t stream) {
  const float* src = (const float*)d_in[0];
  const int*   slen = (const int*)d_in[1];
  const float* tgt = (const float*)d_in[2];
  const int*   tlen = (const int*)d_in[3];
  const float* W1 = (const float*)d_in[4];
  const float* b1 = (const float*)d_in[5];
  const float* W2 = (const float*)d_in[6];
  const float* b2 = (const float*)d_in[7];
  float* out = (float*)d_out;

  float* ps  = (float*)d_ws;                 // 512*640 f32
  float* pt  = ps + 512 * 640;               // 256*640 f32
  uint4* w2p = (uint4*)(pt + 256 * 640);     // 80*1024 uint4 (bf16 packed W2)

  k_pack_w2<<<80, 256, 0, stream>>>(W2, w2p, slen, tlen,
                                    out + (size_t)B_ * T_ * U_ * V_);
  k_proj<<<192, 640, 0, stream>>>(src, tgt, W1, b1, ps, pt);
  k_joint<<<512, 1024, 0, stream>>>(ps, pt, w2p, b2, out);
}